// Round 9
// baseline (1861.749 us; speedup 1.0000x reference)
//
#include <hip/hip_runtime.h>

#define NORI 8
#define KS 7
#define CH 32
#define IMG 224
#define STRIP 16
#define SROWS 22            // STRIP + 6 halo rows
#define PITCH 232           // floats/row; col j holds x-col (j-4); cols 0-3 & 228-231 stay 0
#define BUF (SROWS * PITCH) // 5104 floats per buffer

typedef float f4 __attribute__((ext_vector_type(4)));

__global__ __launch_bounds__(512, 4)
void gabor_dw_conv(const float* __restrict__ x, const float* __restrict__ filt,
                   float* __restrict__ out) {
    __shared__ __align__(16) float s_in[2 * BUF + 64];   // +pad for lane>=56 stray reads

    const int bid = blockIdx.x;              // plane 0..511 (no inter-block reuse -> no swizzle)
    const int c = bid & (CH - 1);
    const int b = bid >> 5;

    const int tid = threadIdx.x;
    const int wv  = tid >> 6;                // wave 0..7 = orientation
    const int l   = tid & 63;

    const float* xp = x + (size_t)(b * CH + c) * (IMG * IMG);
    const int gxw = l - 1;                   // global float4 index covered by this lane
    const bool lok = (l >= 1) && (l <= 56);  // staging lanes (f4s 0..55 -> LDS cols 4..227)

    // zero both buffers once: halo cols 0-3 / 228-231 are never rewritten -> stay 0 forever
    for (int i = tid; i < (2 * BUF + 64) / 4; i += 512)
        *(f4*)&s_in[4 * i] = (f4)0.f;

    // weights -> SGPRs (wave-uniform address; R7 win), loaded ONCE per plane
    const int wbase = __builtin_amdgcn_readfirstlane((c * NORI + wv) * 49);
    float w[49];
    #pragma unroll
    for (int k = 0; k < 49; ++k) w[k] = filt[wbase + k];

    __syncthreads();

    // stage strip 0 into buffer 0 (rows gy = -3..18; wave wv stages rows 3wv..3wv+2)
    #pragma unroll
    for (int k = 0; k < 3; ++k) {
        const int r = 3 * wv + k;
        const int gy = r - 3;
        if (lok && r < SROWS) {
            f4 v = (f4)0.f;
            if (gy >= 0 && gy < IMG) v = *(const f4*)(xp + gy * IMG + 4 * gxw);
            *(f4*)&s_in[r * PITCH + 4 * l] = v;
        }
    }
    __syncthreads();

    float* const op = out + (size_t)(b * (CH * NORI) + c * NORI + wv) * (IMG * IMG) + 4 * l;
    const bool sok = (l < 56);               // compute/store lanes

    float acc[8][4];                         // ring of 8 out-row accumulators (no init:
    float W[2][12];                          //  first tap (ky==0,kx==0) overwrites)
    int cur = 0;

#define RDW(WI, R) do {                                                     \
    const f4* p_ = (const f4*)&bp[(R) * PITCH + 4 * l];                     \
    f4 u0 = p_[0], u1 = p_[1], u2 = p_[2];                                  \
    W[WI][0]=u0.x; W[WI][1]=u0.y; W[WI][2]=u0.z;  W[WI][3]=u0.w;            \
    W[WI][4]=u1.x; W[WI][5]=u1.y; W[WI][6]=u1.z;  W[WI][7]=u1.w;            \
    W[WI][8]=u2.x; W[WI][9]=u2.y; W[WI][10]=u2.z; W[WI][11]=u2.w; } while (0)

#define TAPS(WI, MM, KYMIN, KYMAX)                                          \
    _Pragma("unroll")                                                       \
    for (int ky = (KYMIN); ky <= (KYMAX); ++ky) {                           \
        const int s_ = ((MM) - ky) & 7;          /* static after unroll */  \
        _Pragma("unroll")                                                   \
        for (int kx = 0; kx < KS; ++kx) {                                   \
            const float cw_ = w[ky * 7 + kx];    /* SGPR operand */         \
            _Pragma("unroll")                                               \
            for (int p = 0; p < 4; ++p) {                                   \
                if (ky == 0 && kx == 0) acc[s_][p] = W[WI][p + 1] * cw_;    \
                else acc[s_][p] += W[WI][p + kx + 1] * cw_;                 \
            }                                                               \
        }                                                                   \
    }

#define ST(MM, JR) do {                                                     \
    if (sok) {                                                              \
        const int ss_ = ((MM) + 2) & 7;                                     \
        f4 v_; v_.x = acc[ss_][0]; v_.y = acc[ss_][1];                      \
        v_.z = acc[ss_][2]; v_.w = acc[ss_][3];                             \
        *(f4*)(ops + (size_t)(JR) * IMG) = v_;   /* no nt: let L2 merge */  \
    } } while (0)

#define FENCE __builtin_amdgcn_sched_barrier(0)

    #pragma clang loop unroll(disable)
    for (int s = 0; s < 14; ++s) {
        // T14 async-stage: issue next strip's loads NOW, consume after compute
        f4 ld[3];
        {
            const int gyb = 16 * s + 13;         // = 16(s+1) - 3, always >= 13
            #pragma unroll
            for (int k = 0; k < 3; ++k) {
                const int r = 3 * wv + k;
                const int gy = gyb + r;
                ld[k] = (f4)0.f;
                if (lok && r < SROWS && gy < IMG)
                    ld[k] = *(const f4*)(xp + gy * IMG + 4 * gxw);
            }
        }

        const float* bp = &s_in[cur * BUF];
        float* const ops = op + (size_t)(16 * s) * IMG;

        // 22-row sweep; row r computes on W[r&1] (prefetched 1 row ahead)
        RDW(0, 0);
        RDW(1, 1);  TAPS(0, 0, 0, 0);
        RDW(0, 2);  TAPS(1, 1, 0, 1);            FENCE;
        RDW(1, 3);  TAPS(0, 2, 0, 2);
        RDW(0, 4);  TAPS(1, 3, 0, 3);            FENCE;
        RDW(1, 5);  TAPS(0, 4, 0, 4);
        RDW(0, 6);  TAPS(1, 5, 0, 5);            FENCE;
        RDW(1, 7);  TAPS(0, 6, 0, 6);  ST(6, 0);
        RDW(0, 8);  TAPS(1, 7, 0, 6);  ST(7, 1); FENCE;
        RDW(1, 9);  TAPS(0, 0, 0, 6);  ST(0, 2);
        RDW(0, 10); TAPS(1, 1, 0, 6);  ST(1, 3); FENCE;
        RDW(1, 11); TAPS(0, 2, 0, 6);  ST(2, 4);
        RDW(0, 12); TAPS(1, 3, 0, 6);  ST(3, 5); FENCE;
        RDW(1, 13); TAPS(0, 4, 0, 6);  ST(4, 6);
        RDW(0, 14); TAPS(1, 5, 0, 6);  ST(5, 7); FENCE;
        RDW(1, 15); TAPS(0, 6, 0, 6);  ST(6, 8);
        RDW(0, 16); TAPS(1, 7, 0, 6);  ST(7, 9); FENCE;
        RDW(1, 17); TAPS(0, 0, 1, 6);  ST(0, 10);
        RDW(0, 18); TAPS(1, 1, 2, 6);  ST(1, 11); FENCE;
        RDW(1, 19); TAPS(0, 2, 3, 6);  ST(2, 12);
        RDW(0, 20); TAPS(1, 3, 4, 6);  ST(3, 13); FENCE;
        RDW(1, 21); TAPS(0, 4, 5, 6);  ST(4, 14);
                    TAPS(1, 5, 6, 6);  ST(5, 15); FENCE;

        // deliver staged rows into the other buffer (vmcnt hidden under the sweep)
        {
            float* wp_ = &s_in[(cur ^ 1) * BUF];
            #pragma unroll
            for (int k = 0; k < 3; ++k) {
                const int r = 3 * wv + k;
                if (lok && r < SROWS)
                    *(f4*)&wp_[r * PITCH + 4 * l] = ld[k];
            }
        }
        __syncthreads();
        cur ^= 1;
    }

#undef RDW
#undef TAPS
#undef ST
#undef FENCE
}

extern "C" void kernel_launch(void* const* d_in, const int* in_sizes, int n_in,
                              void* d_out, int out_size, void* d_ws, size_t ws_size,
                              hipStream_t stream) {
    const float* x = (const float*)d_in[0];
    const float* filt = (const float*)d_in[1];
    float* out = (float*)d_out;

    dim3 grid(CH * 16);        // 512 planes; 2 blocks/CU exactly, one launch round
    dim3 block(512);           // 8 waves = 8 orientations
    gabor_dw_conv<<<grid, block, 0, stream>>>(x, filt, out);
}

// Round 10
// 258.803 us; speedup vs baseline: 7.1937x; 7.1937x over previous
//
#include <hip/hip_runtime.h>

#define NORI 8
#define KS 7
#define CH 32
#define IMG 224
#define STRIP 32           // output rows per block
#define SROWS (STRIP + 6)  // staged input rows = 38
#define PITCH 232          // floats per staged row; col j holds x-col (j-4)

typedef float f4 __attribute__((ext_vector_type(4)));

// R9 lesson: launch_bounds(512,4) -> waves-per-eu=4,8 and the RA targets the
// MAX (8/EU = 64-VGPR budget), spilling to reach it. Pin min=max=4 so the
// allocator gets a 128-VGPR budget and allocates the ~80 the code needs.
__global__ void __attribute__((amdgpu_flat_work_group_size(512, 512),
                               amdgpu_waves_per_eu(4, 4)))
gabor_dw_conv(const float* __restrict__ x, const float* __restrict__ filt,
              float* __restrict__ out) {
    __shared__ __align__(16) float s_in[SROWS * PITCH];   // 38*232*4 = 35264 B

    // bijective XCD swizzle: nwg = 7*32*16 = 3584 = 8 * 448 exactly
    const int cpx = (7 * CH * 16) / 8;           // 448
    const int bid = blockIdx.x;
    const int logical = (bid & 7) * cpx + (bid >> 3);
    const int strip = logical % 7;               // strips of a plane adjacent in time
    const int plane = logical / 7;               // 0..511
    const int c = plane & (CH - 1);
    const int b = plane >> 5;
    const int gy0 = strip * STRIP;

    const int tid = threadIdx.x;
    const int wv  = tid >> 6;                    // wave 0..7 = orientation
    const int l   = tid & 63;

    // ---- stage input rows gy0-3 .. gy0+34 (coalesced 896B/row) ----
    const float* xp = x + (size_t)(b * CH + c) * (IMG * IMG);
    {
        const int gxw = l - 1;                   // float4 index in global row
        const bool xok = (gxw >= 0) && (gxw < IMG / 4);
        for (int row = wv; row < SROWS; row += 8) {
            int gy = gy0 - 3 + row;
            f4 v = (f4)0.f;
            if (xok && gy >= 0 && gy < IMG) v = *(const f4*)(xp + gy * IMG + 4 * gxw);
            if (l < 58) *(f4*)&s_in[row * PITCH + 4 * l] = v;
        }
    }

    // ---- weights into SGPRs (wave-uniform address; round-7 win) ----
    const int wbase = __builtin_amdgcn_readfirstlane((c * NORI + wv) * 49);
    float w[49];
    #pragma unroll
    for (int k = 0; k < 49; ++k) w[k] = filt[wbase + k];

    __syncthreads();
    if (l >= 56) return;                         // 56 lanes x 4 px = 224

    float* op = out + ((size_t)(b * (CH * NORI) + c * NORI + wv) * IMG + gy0) * IMG + 4 * l;

    // ---- input-stationary sweep, ring of 8 accumulators.
    // Row i feeds out rows j = i-ky (ky=0..6); slot = j&7 = (m-ky)&7, m = i&7
    // -> ALL register indices compile-time (R5 lesson). Steady phase is a REAL
    // loop of 8-row groups (R6 lesson: bounded scheduler scope).
    float acc[8][4] = {{0,0,0,0},{0,0,0,0},{0,0,0,0},{0,0,0,0},
                       {0,0,0,0},{0,0,0,0},{0,0,0,0},{0,0,0,0}};
    float W[12];

#define RDW(IRT) do {                                                       \
    const f4* p_ = (const f4*)&s_in[(IRT) * PITCH + 4 * l];                 \
    f4 u0 = p_[0], u1 = p_[1], u2 = p_[2];                                  \
    W[0]=u0.x; W[1]=u0.y; W[2]=u0.z;  W[3]=u0.w;                            \
    W[4]=u1.x; W[5]=u1.y; W[6]=u1.z;  W[7]=u1.w;                            \
    W[8]=u2.x; W[9]=u2.y; W[10]=u2.z; W[11]=u2.w; } while (0)

#define TAPS(MM, KYMIN, KYMAX)                                              \
    _Pragma("unroll")                                                       \
    for (int ky = (KYMIN); ky <= (KYMAX); ++ky) {                           \
        const int s_ = ((MM) - ky) & 7;          /* static after unroll */  \
        _Pragma("unroll")                                                   \
        for (int kx = 0; kx < KS; ++kx) {                                   \
            const float cw_ = w[ky * 7 + kx];    /* SGPR operand */         \
            _Pragma("unroll")                                               \
            for (int p = 0; p < 4; ++p)                                     \
                acc[s_][p] += W[p + kx + 1] * cw_;                          \
        }                                                                   \
    }

#define STORE_SLOT(MM, JROW) do {                /* slot (i-6)&7=(MM+2)&7 */\
    const int ss_ = ((MM) + 2) & 7;                                         \
    f4 v_; v_.x = acc[ss_][0]; v_.y = acc[ss_][1];                          \
    v_.z = acc[ss_][2]; v_.w = acc[ss_][3];                                 \
    __builtin_nontemporal_store(v_, (f4*)(op + (size_t)(JROW) * IMG));      \
    acc[ss_][0] = 0.f; acc[ss_][1] = 0.f;                                   \
    acc[ss_][2] = 0.f; acc[ss_][3] = 0.f; } while (0)

#define FENCE __builtin_amdgcn_sched_barrier(0)

    // prologue: rows 0..7 (taps ky <= i; stores start at i=6)
    RDW(0); TAPS(0, 0, 0);
    RDW(1); TAPS(1, 0, 1); FENCE;
    RDW(2); TAPS(2, 0, 2);
    RDW(3); TAPS(3, 0, 3); FENCE;
    RDW(4); TAPS(4, 0, 4);
    RDW(5); TAPS(5, 0, 5); FENCE;
    RDW(6); TAPS(6, 0, 6); STORE_SLOT(6, 0);
    RDW(7); TAPS(7, 0, 6); STORE_SLOT(7, 1); FENCE;

    // steady: rows 8..31, groups of 8 (slot pattern period 8 -> all static)
    #pragma clang loop unroll(disable)
    for (int g = 1; g <= 3; ++g) {
        const int i0 = 8 * g;
        RDW(i0 + 0); TAPS(0, 0, 6); STORE_SLOT(0, i0 - 6);
        RDW(i0 + 1); TAPS(1, 0, 6); STORE_SLOT(1, i0 - 5); FENCE;
        RDW(i0 + 2); TAPS(2, 0, 6); STORE_SLOT(2, i0 - 4);
        RDW(i0 + 3); TAPS(3, 0, 6); STORE_SLOT(3, i0 - 3); FENCE;
        RDW(i0 + 4); TAPS(4, 0, 6); STORE_SLOT(4, i0 - 2);
        RDW(i0 + 5); TAPS(5, 0, 6); STORE_SLOT(5, i0 - 1); FENCE;
        RDW(i0 + 6); TAPS(6, 0, 6); STORE_SLOT(6, i0 + 0);
        RDW(i0 + 7); TAPS(7, 0, 6); STORE_SLOT(7, i0 + 1); FENCE;
    }

    // epilogue: rows 32..37 (taps ky >= i-31; stores j = 26..31)
    RDW(32); TAPS(0, 1, 6); STORE_SLOT(0, 26);
    RDW(33); TAPS(1, 2, 6); STORE_SLOT(1, 27); FENCE;
    RDW(34); TAPS(2, 3, 6); STORE_SLOT(2, 28);
    RDW(35); TAPS(3, 4, 6); STORE_SLOT(3, 29); FENCE;
    RDW(36); TAPS(4, 5, 6); STORE_SLOT(4, 30);
    RDW(37); TAPS(5, 6, 6); STORE_SLOT(5, 31);

#undef RDW
#undef TAPS
#undef STORE_SLOT
#undef FENCE
}

extern "C" void kernel_launch(void* const* d_in, const int* in_sizes, int n_in,
                              void* d_out, int out_size, void* d_ws, size_t ws_size,
                              hipStream_t stream) {
    const float* x = (const float*)d_in[0];
    const float* filt = (const float*)d_in[1];
    float* out = (float*)d_out;

    dim3 grid(7 * CH * 16);    // y-strips * channels * batch = 3584
    dim3 block(512);           // 8 waves = 8 orientations
    gabor_dw_conv<<<grid, block, 0, stream>>>(x, filt, out);
}